// Round 1
// 420.143 us; speedup vs baseline: 1.0065x; 1.0065x over previous
//
#include <hip/hip_runtime.h>
#include <math.h>

#define N_IMG 32
#define N_ATOM 400000
#define NE (N_ATOM*3)        // 1,200,000 floats per image row
#define NE4 (NE/4)           // 300,000 float4 per image row
#define KMAXC 0.1f
#define DLTKC 0.02f
#define EPSE 0.1f

// global sums layout (ws floats [0..150]):
#define OFF_SDD 0    // 31 per-link |d|^2
#define OFF_SPM 31   // 30 d[j-1].d[j]
#define OFF_SFP 61   // 30 f[j].d[j-1]
#define OFF_SFM 91   // 30 f[j].d[j]
#define OFF_SFF 121  // 30 |f[j]|^2
#define NSUM 151
#define OFF_CO  160  // coeffs A[30],B[30],C[30] at ws[160..249]
#define OFF_PART 256 // per-block partials: NBXP rows x 160 floats
#define PSTRIDE 160

#define NBXP 586     // pass1 column-blocks (2 float4 cols per thread)
#define NBX2 1172    // pass2 column-blocks (1 float4 col per thread)
#define NCHUNK 5     // 5 chunks x 6 interior images = images 1..30

__device__ __forceinline__ float dot4(float4 a, float4 b) {
    return a.x*b.x + a.y*b.y + a.z*b.z + a.w*b.w;
}
__device__ __forceinline__ float4 sub4(float4 a, float4 b) {
    return make_float4(a.x-b.x, a.y-b.y, a.z-b.z, a.w-b.w);
}

// Full-wave (64-lane) sum via DPP on the VALU pipe. Lane 63 has the total.
__device__ __forceinline__ float wred_dpp(float x) {
    x += __int_as_float(__builtin_amdgcn_update_dpp(0, __float_as_int(x), 0x111, 0xf, 0xf, false)); // row_shr:1
    x += __int_as_float(__builtin_amdgcn_update_dpp(0, __float_as_int(x), 0x112, 0xf, 0xf, false)); // row_shr:2
    x += __int_as_float(__builtin_amdgcn_update_dpp(0, __float_as_int(x), 0x114, 0xf, 0xf, false)); // row_shr:4
    x += __int_as_float(__builtin_amdgcn_update_dpp(0, __float_as_int(x), 0x118, 0xf, 0xf, false)); // row_shr:8
    x += __int_as_float(__builtin_amdgcn_update_dpp(0, __float_as_int(x), 0x142, 0xa, 0xf, false)); // row_bcast:15
    x += __int_as_float(__builtin_amdgcn_update_dpp(0, __float_as_int(x), 0x143, 0xc, 0xf, false)); // row_bcast:31
    return x;
}

// grid: (NBXP, NCHUNK). Chunk c handles interior images j0..j0+5, j0 = 1+6c.
// All 14 float4 loads per column are issued up-front into explicit arrays so
// the compiler keeps them in flight together (MLP), instead of serializing
// into vmcnt groups under a 64-VGPR budget. launch_bounds(256,3) allows up
// to ~170 VGPRs (3 waves/SIMD min) — enough for 14 in-flight loads + 31 acc.
__global__ __launch_bounds__(256, 3) void eb_pass1(const float* __restrict__ pos,
                                                   const float* __restrict__ frc,
                                                   float* __restrict__ part) {
    const int c = blockIdx.y;
    const int j0 = 1 + 6 * c;
    const float4* pos4 = reinterpret_cast<const float4*>(pos);
    const float4* frc4 = reinterpret_cast<const float4*>(frc);

    float sdd[7], spm[6], sfp[6], sfm[6], sff[6];
#pragma unroll
    for (int i = 0; i < 7; ++i) sdd[i] = 0.f;
#pragma unroll
    for (int i = 0; i < 6; ++i) { spm[i] = 0.f; sfp[i] = 0.f; sfm[i] = 0.f; sff[i] = 0.f; }

    for (int t = blockIdx.x * 256 + threadIdx.x; t < NE4; t += 256 * NBXP) {
        float4 p[8], f[6];
#pragma unroll
        for (int i = 0; i < 8; ++i) p[i] = pos4[(size_t)(j0 - 1 + i) * NE4 + t];
#pragma unroll
        for (int i = 0; i < 6; ++i) f[i] = frc4[(size_t)(j0 + i) * NE4 + t];
        float4 d[7];
#pragma unroll
        for (int i = 0; i < 7; ++i) d[i] = sub4(p[i + 1], p[i]);   // d[i] = link (j0-1+i)
#pragma unroll
        for (int i = 0; i < 7; ++i) sdd[i] += dot4(d[i], d[i]);
#pragma unroll
        for (int jj = 0; jj < 6; ++jj) {
            spm[jj] += dot4(d[jj], d[jj + 1]);   // d[j-1].d[j]
            sfp[jj] += dot4(f[jj], d[jj]);       // f.d[j-1]
            sfm[jj] += dot4(f[jj], d[jj + 1]);   // f.d[j]
            sff[jj] += dot4(f[jj], f[jj]);
        }
    }

    // pack into one array for the block reduction
    float v[31];
#pragma unroll
    for (int i = 0; i < 7; ++i) v[i] = sdd[i];
#pragma unroll
    for (int i = 0; i < 6; ++i) { v[7 + i] = spm[i]; v[13 + i] = sfp[i]; v[19 + i] = sfm[i]; v[25 + i] = sff[i]; }

    __shared__ float red[4][31];
    const int wave = threadIdx.x >> 6;
    const int lane = threadIdx.x & 63;
#pragma unroll
    for (int s = 0; s < 31; ++s) {
        float r = wred_dpp(v[s]);
        if (lane == 63) red[wave][s] = r;
    }
    __syncthreads();
    const int s = threadIdx.x;
    if (s < 31) {
        float r = red[0][s] + red[1][s] + red[2][s] + red[3][s];
        int slot; bool owned = true;
        if (s < 7)       { owned = (s < 6) || (c == NCHUNK - 1); slot = OFF_SDD + (j0 - 1) + s; }
        else if (s < 13) slot = OFF_SPM + (j0 - 1) + (s - 7);
        else if (s < 19) slot = OFF_SFP + (j0 - 1) + (s - 13);
        else if (s < 25) slot = OFF_SFM + (j0 - 1) + (s - 19);
        else             slot = OFF_SFF + (j0 - 1) + (s - 25);
        if (owned) part[(size_t)blockIdx.x * PSTRIDE + slot] = r;
    }
}

// grid: (NSUM, 1). Block b sums partials column b over NBXP rows -> sums[b].
__global__ __launch_bounds__(256) void eb_reduce(const float* __restrict__ part,
                                                 float* __restrict__ sums) {
    const int s = blockIdx.x;
    float acc = 0.f;
    for (int r = threadIdx.x; r < NBXP; r += 256)
        acc += part[(size_t)r * PSTRIDE + s];
    __shared__ float red[4];
    const int wave = threadIdx.x >> 6;
    const int lane = threadIdx.x & 63;
    float v = wred_dpp(acc);
    if (lane == 63) red[wave] = v;
    __syncthreads();
    if (threadIdx.x == 0) sums[s] = red[0] + red[1] + red[2] + red[3];
}

__global__ void eb_coeff(const float* __restrict__ eng,
                         const float* __restrict__ sums,
                         float* __restrict__ co) {
    const int jj = threadIdx.x;        // one interior image per thread
    if (jj >= N_IMG - 2 || blockIdx.x != 0) return;
    float e[N_IMG];
    float emin = 1e30f, emax = -1e30f;
    int imax = 0;
    for (int i = 0; i < N_IMG; ++i) {
        float v = eng[i];
        e[i] = v;
        if (v < emin) emin = v;
        if (v > emax) { emax = v; imax = i; }   // strict > -> first max = argmax
    }
    const float eref = emin - EPSE;
    float e0 = e[jj], e1 = e[jj + 1], e2 = e[jj + 2];
    float eim = fmaxf(e1, e0);
    float km = KMAXC - DLTKC * (emax - eim) / (emax - eref);
    if (eim < eref) km = KMAXC - DLTKC;
    float eip = fmaxf(e2, e1);
    float kp = KMAXC - DLTKC * (emax - eip) / (emax - eref);
    if (eip < eref) kp = KMAXC - DLTKC;

    float pp = (e2 > e1 && e1 > e0) ? 1.f : 0.f;
    float mm = (e2 < e1 && e1 < e0) ? 1.f : 0.f;
    float nb = 1.f - fmaxf(pp, mm);
    float mp = ((e2 > e1) ? 1.f : 0.f) * nb;
    float mq = ((e2 < e1) ? 1.f : 0.f) * nb;
    float dvmax = fmaxf(fabsf(e2 - e1), fabsf(e0 - e1));
    float dvmin = fminf(fabsf(e2 - e1), fabsf(e0 - e1));
    float a = pp + dvmax * mp + dvmin * mq;   // coeff of tau_p
    float b = mm + dvmin * mp + dvmax * mq;   // coeff of tau_m
    float Spp = sums[OFF_SDD + jj];
    float Smm = sums[OFF_SDD + jj + 1];
    float Spm = sums[OFF_SPM + jj];
    float Sfp = sums[OFF_SFP + jj];
    float Sfm = sums[OFF_SFM + jj];
    float Sff = sums[OFF_SFF + jj];
    float ntau2 = a * a * Spp + 2.f * a * b * Spm + b * b * Smm;
    float ntau = sqrtf(ntau2);
    float ta = a / ntau, tb = b / ntau;
    float fpar = ta * Sfp + tb * Sfm;                       // dot(frc, tau)
    float spar = kp * sqrtf(Smm) - km * sqrtf(Spp);         // spr_para magnitude
    float ffpp = Sff - fpar * fpar;                         // |frc_perp|^2
    float strau = ta * (kp * Spm - km * Spp) + tb * (kp * Smm - km * Spm); // dot(spr,tau)
    float Sss = kp * kp * Smm - 2.f * kp * km * Spm + km * km * Spp;       // dot(spr,spr)
    float sspp = Sss - 2.f * spar * strau + spar * spar;    // |spr_perp|^2
    float Ssf = kp * Sfm - km * Sfp;                        // dot(spr,frc)
    float spfp = Ssf - fpar * strau;                        // dot(spr_perp,frc_perp)
    float sw = (2.0f / 3.14159265358979323846f) * atan2f(ffpp, sspp);
    float cc = spfp * sw;
    float g = (jj == imax) ? 2.f : 1.f;                     // .at[i_raw].multiply(2.0)
    float w = (cc - g) * fpar / ntau;
    co[jj]      = 1.f - cc;       // A: coeff of frc
    co[30 + jj] = kp + w * b;     // B: coeff of tau_m (=d[j])
    co[60 + jj] = w * a - km;     // C: coeff of tau_p (=d[j-1])
}

// grid: (NBX2, NCHUNK). Chunk c writes out rows j0..j0+5.
// Same load-all-up-front restructure as pass1: 14 independent float4 loads
// in flight before any compute/store.
__global__ __launch_bounds__(256, 4) void eb_pass2(const float* __restrict__ pos,
                                                   const float* __restrict__ frc,
                                                   const float* __restrict__ co,
                                                   float* __restrict__ out) {
    __shared__ float A[30], B[30], C[30];
    if (threadIdx.x < 30) {
        A[threadIdx.x] = co[threadIdx.x];
        B[threadIdx.x] = co[30 + threadIdx.x];
        C[threadIdx.x] = co[60 + threadIdx.x];
    }
    __syncthreads();
    const int t = blockIdx.x * 256 + threadIdx.x;
    if (t >= NE4) return;
    const int c = blockIdx.y;
    const int j0 = 1 + 6 * c;
    const float4* pos4 = reinterpret_cast<const float4*>(pos);
    const float4* frc4 = reinterpret_cast<const float4*>(frc);
    float4* out4 = reinterpret_cast<float4*>(out);

    float4 p[8], f[6];
#pragma unroll
    for (int i = 0; i < 8; ++i) p[i] = pos4[(size_t)(j0 - 1 + i) * NE4 + t];
#pragma unroll
    for (int i = 0; i < 6; ++i) f[i] = frc4[(size_t)(j0 + i) * NE4 + t];

    if (c == 0) out4[t] = frc4[t];                                       // out[0]=frc[0]
    if (c == NCHUNK - 1) {
        size_t i31 = (size_t)31 * NE4 + t;
        out4[i31] = frc4[i31];                                           // out[31]=frc[31]
    }

    float4 d[7];
#pragma unroll
    for (int i = 0; i < 7; ++i) d[i] = sub4(p[i + 1], p[i]);   // d[i] = link (j0-1+i)
#pragma unroll
    for (int jj = 0; jj < 6; ++jj) {
        const int j = j0 + jj;
        const int g = j - 1;
        float ca = A[g], cb = B[g], cd = C[g];
        float4 o;
        o.x = ca * f[jj].x + cb * d[jj + 1].x + cd * d[jj].x;
        o.y = ca * f[jj].y + cb * d[jj + 1].y + cd * d[jj].y;
        o.z = ca * f[jj].z + cb * d[jj + 1].z + cd * d[jj].z;
        o.w = ca * f[jj].w + cb * d[jj + 1].w + cd * d[jj].w;
        out4[(size_t)j * NE4 + t] = o;
    }
}

extern "C" void kernel_launch(void* const* d_in, const int* in_sizes, int n_in,
                              void* d_out, int out_size, void* d_ws, size_t ws_size,
                              hipStream_t stream) {
    const float* pos = (const float*)d_in[0];
    const float* frc = (const float*)d_in[1];
    const float* eng = (const float*)d_in[2];
    float* out = (float*)d_out;
    float* ws = (float*)d_ws;
    float* sums = ws;                 // [0..150]
    float* co   = ws + OFF_CO;        // [160..249]
    float* part = ws + OFF_PART;      // NBXP x PSTRIDE

    eb_pass1<<<dim3(NBXP, NCHUNK), 256, 0, stream>>>(pos, frc, part);
    eb_reduce<<<NSUM, 256, 0, stream>>>(part, sums);
    eb_coeff<<<1, 64, 0, stream>>>(eng, sums, co);
    eb_pass2<<<dim3(NBX2, NCHUNK), 256, 0, stream>>>(pos, frc, co, out);
}